// Round 1
// baseline (341.044 us; speedup 1.0000x reference)
//
#include <hip/hip_runtime.h>
#include <hip/hip_bf16.h>
#include <stdint.h>

// ---------------------------------------------------------------------------
// UpdateSpeaker: GRU-like gating block.
//   r,p,z = sigmoid(X@Wx*^T + S@Wh*^T + A@Vh*^T)
//   h~    = tanh(X@Wxh^T + (r*S)@Whh^T + (p*A)@Vhh^T)
//   out   = (1-z)*S + z*h~
// Strategy: bf16 MFMA GEMMs (m97 128^2 structure) with fused gate epilogues.
// ---------------------------------------------------------------------------

typedef short  short8  __attribute__((ext_vector_type(8)));
typedef unsigned short ushort8 __attribute__((ext_vector_type(8)));
typedef float  f32x4   __attribute__((ext_vector_type(4)));

static constexpr int Bn  = 16384;  // batch
static constexpr int HID = 1024;
static constexpr int UD  = 512;

// ---- helpers --------------------------------------------------------------

__device__ __forceinline__ unsigned short f2bf(float x) {
  union { float f; unsigned u; } v; v.f = x;
  unsigned r = v.u + 0x7fffu + ((v.u >> 16) & 1u);   // RNE
  return (unsigned short)(r >> 16);
}
__device__ __forceinline__ float bf2f(unsigned short h) {
  union { unsigned u; float f; } v; v.u = ((unsigned)h) << 16; return v.f;
}
__device__ __forceinline__ float sigm(float x) { return 1.0f / (1.0f + __expf(-x)); }
__device__ __forceinline__ float tanh_fast(float x) {
  return 2.0f / (1.0f + __expf(-2.0f * x)) - 1.0f;   // safe at +-inf
}

typedef __attribute__((address_space(1))) const char gchar_t;
typedef __attribute__((address_space(3))) char       lchar_t;
__device__ __forceinline__ void gload_lds16(const void* g, void* l) {
  __builtin_amdgcn_global_load_lds((const __attribute__((address_space(1))) void*)g,
                                   (__attribute__((address_space(3))) void*)l,
                                   16, 0, 0);
}

// ---- weight packing -------------------------------------------------------
// W1: (2048 x 2048) bf16. Row n: gate g=n>>9, j=n&511.
//   k in [0,1024)   : WA_x{g}[j][k]
//   k in [1024,1536): g<3 ? WA_h{g}[j][k-1024] : 0
//   k in [1536,2048): g<3 ? VA_h{g}[j][k-1536] : 0
__global__ __launch_bounds__(256) void pack_w1(
    const float* __restrict__ xr, const float* __restrict__ xp,
    const float* __restrict__ xz, const float* __restrict__ xh,
    const float* __restrict__ hr, const float* __restrict__ hp, const float* __restrict__ hz,
    const float* __restrict__ vr, const float* __restrict__ vp, const float* __restrict__ vz,
    unsigned short* __restrict__ W1)
{
  int idx = blockIdx.x * 256 + threadIdx.x;       // 2048 rows * 256 chunks
  int n  = idx >> 8;
  int k8 = (idx & 255) << 3;
  int g = n >> 9, j = n & 511;
  const float* src = nullptr;
  if (k8 < 1024) {
    const float* x = (g == 0) ? xr : (g == 1) ? xp : (g == 2) ? xz : xh;
    src = x + (size_t)j * 1024 + k8;
  } else if (k8 < 1536) {
    if (g < 3) { const float* h = (g == 0) ? hr : (g == 1) ? hp : hz; src = h + (size_t)j * 512 + (k8 - 1024); }
  } else {
    if (g < 3) { const float* v = (g == 0) ? vr : (g == 1) ? vp : vz; src = v + (size_t)j * 512 + (k8 - 1536); }
  }
  ushort8 o;
  if (src) { for (int i = 0; i < 8; i++) o[i] = f2bf(src[i]); }
  else     { for (int i = 0; i < 8; i++) o[i] = 0; }
  *(ushort8*)&W1[(size_t)n * 2048 + k8] = o;
}

// W2: (512 x 1024) bf16 = [Whh | Vhh]
__global__ __launch_bounds__(256) void pack_w2(
    const float* __restrict__ hh, const float* __restrict__ vh,
    unsigned short* __restrict__ W2)
{
  int idx = blockIdx.x * 256 + threadIdx.x;       // 512 rows * 128 chunks
  int n  = idx >> 7;
  int k8 = (idx & 127) << 3;
  const float* src = (k8 < 512) ? hh + (size_t)n * 512 + k8
                                : vh + (size_t)n * 512 + (k8 - 512);
  ushort8 o;
  for (int i = 0; i < 8; i++) o[i] = f2bf(src[i]);
  *(ushort8*)&W2[(size_t)n * 1024 + k8] = o;
}

// U: (B x 2048) bf16 = [X | S | A]
__global__ __launch_bounds__(256) void pack_u(
    const float* __restrict__ X, const float* __restrict__ S, const float* __restrict__ A,
    unsigned short* __restrict__ U)
{
  int idx = blockIdx.x * 256 + threadIdx.x;       // B * 256 chunks
  int b  = idx >> 8;
  int c8 = (idx & 255) << 3;
  const float* src = (c8 < 1024) ? X + (size_t)b * 1024 + c8
                   : (c8 < 1536) ? S + (size_t)b * 512 + (c8 - 1024)
                                 : A + (size_t)b * 512 + (c8 - 1536);
  f32x4 lo = *(const f32x4*)src;
  f32x4 hi = *(const f32x4*)(src + 4);
  ushort8 o;
  o[0] = f2bf(lo[0]); o[1] = f2bf(lo[1]); o[2] = f2bf(lo[2]); o[3] = f2bf(lo[3]);
  o[4] = f2bf(hi[0]); o[5] = f2bf(hi[1]); o[6] = f2bf(hi[2]); o[7] = f2bf(hi[3]);
  *(ushort8*)&U[(size_t)b * 2048 + c8] = o;
}

// ---- GEMM: C = Amat(MxK) @ Bmat(NxK)^T, m97 structure -----------------------
// 128x128 tile, 4 waves (2x2 of 64x64), BK=32, global_load_lds width 16.
// EPI=1: GEMM1 epilogue (gate split). EPI=2: GEMM2 epilogue (final output).
template<int EPI>
__global__ __launch_bounds__(256) void gemm_bt(
    const unsigned short* __restrict__ Amat,
    const unsigned short* __restrict__ Bmat,
    const int K,
    const float* __restrict__ Sv, const float* __restrict__ Av,
    unsigned short* __restrict__ U2, unsigned short* __restrict__ Zp,
    unsigned short* __restrict__ XHp, float* __restrict__ Out)
{
  constexpr int BM = 128, BN = 128, BK = 32;
  __shared__ __align__(16) unsigned short sA[BM * BK];   // 8 KB
  __shared__ __align__(16) unsigned short sB[BN * BK];   // 8 KB

  const int tid  = threadIdx.x;
  const int lane = tid & 63;
  const int wave = tid >> 6;
  const int wr = wave >> 1, wc = wave & 1;               // 2x2 wave grid
  const int m0 = blockIdx.y * BM, n0 = blockIdx.x * BN;
  const int q = tid >> 2, r = tid & 3;                   // staging row / 16B chunk

  const unsigned short* gA = Amat + (size_t)(m0 + q) * K + r * 8;
  const unsigned short* gB = Bmat + (size_t)(n0 + q) * K + r * 8;

  f32x4 acc[4][4] = {};
  const int fr = lane & 15, fq = lane >> 4;

  for (int kt = 0; kt < K; kt += BK) {
    // stage 128x32 A-tile and B-tile (linear LDS: thread t -> bytes [16t,16t+16))
    gload_lds16(gA + kt,                   &sA[tid * 8]);
    gload_lds16(gA + kt + (size_t)64 * K,  &sA[2048 + tid * 8]);
    gload_lds16(gB + kt,                   &sB[tid * 8]);
    gload_lds16(gB + kt + (size_t)64 * K,  &sB[2048 + tid * 8]);
    __syncthreads();   // compiler emits vmcnt(0) drain before barrier

    short8 a[4], b[4];
#pragma unroll
    for (int mt = 0; mt < 4; mt++)
      a[mt] = *(const short8*)&sA[(wr * 64 + mt * 16 + fr) * 32 + fq * 8];
#pragma unroll
    for (int nt = 0; nt < 4; nt++)
      b[nt] = *(const short8*)&sB[(wc * 64 + nt * 16 + fr) * 32 + fq * 8];
#pragma unroll
    for (int mt = 0; mt < 4; mt++)
#pragma unroll
      for (int nt = 0; nt < 4; nt++)
        acc[mt][nt] = __builtin_amdgcn_mfma_f32_16x16x32_bf16(a[mt], b[nt], acc[mt][nt], 0, 0, 0);
    __syncthreads();   // protect LDS before next-tile overwrite
  }

  // Epilogue. D[m][n]: lane holds col = fr, rows = fq*4 + jj (per 16x16 frag).
#pragma unroll
  for (int mt = 0; mt < 4; mt++) {
#pragma unroll
    for (int nt = 0; nt < 4; nt++) {
      const int ncol = n0 + wc * 64 + nt * 16 + fr;
#pragma unroll
      for (int jj = 0; jj < 4; jj++) {
        const int brow = m0 + wr * 64 + mt * 16 + fq * 4 + jj;
        const float v = acc[mt][nt][jj];
        const size_t rb = (size_t)brow;
        if (EPI == 1) {
          const int gate = ncol >> 9, j = ncol & 511;
          if (gate == 0)      U2[rb * 1024 + j]       = f2bf(sigm(v) * Sv[rb * 512 + j]);   // rs
          else if (gate == 1) U2[rb * 1024 + 512 + j] = f2bf(sigm(v) * Av[rb * 512 + j]);   // pa
          else if (gate == 2) Zp[rb * 512 + j]  = f2bf(v);                                  // z preact
          else                XHp[rb * 512 + j] = f2bf(v);                                  // xh preact
        } else {
          const size_t o = rb * 512 + ncol;
          const float z = sigm(bf2f(Zp[o]));
          const float h = tanh_fast(bf2f(XHp[o]) + v);
          Out[o] = (1.0f - z) * Sv[o] + z * h;
        }
      }
    }
  }
}

// ---------------------------------------------------------------------------

extern "C" void kernel_launch(void* const* d_in, const int* in_sizes, int n_in,
                              void* d_out, int out_size, void* d_ws, size_t ws_size,
                              hipStream_t stream) {
  const float* X   = (const float*)d_in[0];
  const float* S   = (const float*)d_in[1];
  const float* A   = (const float*)d_in[2];
  const float* Wxr = (const float*)d_in[3];
  const float* Wxp = (const float*)d_in[4];
  const float* Wxz = (const float*)d_in[5];
  const float* Wxh = (const float*)d_in[6];
  const float* Whr = (const float*)d_in[7];
  const float* Whp = (const float*)d_in[8];
  const float* Whz = (const float*)d_in[9];
  const float* Whh = (const float*)d_in[10];
  const float* Vhr = (const float*)d_in[11];
  const float* Vhp = (const float*)d_in[12];
  const float* Vhz = (const float*)d_in[13];
  const float* Vhh = (const float*)d_in[14];

  char* ws = (char*)d_ws;
  size_t off = 0;
  auto alloc = [&](size_t bytes) -> void* {
    void* p = ws + off;
    off += (bytes + 255) & ~(size_t)255;
    return p;
  };
  unsigned short* W1 = (unsigned short*)alloc((size_t)2048 * 2048 * 2);  // 8.4 MB
  unsigned short* W2 = (unsigned short*)alloc((size_t)512 * 1024 * 2);   // 1 MB
  unsigned short* U  = (unsigned short*)alloc((size_t)Bn * 2048 * 2);    // 67 MB
  unsigned short* U2 = (unsigned short*)alloc((size_t)Bn * 1024 * 2);    // 33.5 MB
  unsigned short* Zp = (unsigned short*)alloc((size_t)Bn * 512 * 2);     // 16.8 MB
  unsigned short* XH = (unsigned short*)alloc((size_t)Bn * 512 * 2);     // 16.8 MB

  pack_w1<<<2048, 256, 0, stream>>>(Wxr, Wxp, Wxz, Wxh, Whr, Whp, Whz, Vhr, Vhp, Vhz, W1);
  pack_w2<<<256, 256, 0, stream>>>(Whh, Vhh, W2);
  pack_u <<<Bn, 256, 0, stream>>>(X, S, A, U);

  // GEMM1: P = U(16384x2048) @ W1^T(2048x2048), fused gate epilogue
  gemm_bt<1><<<dim3(2048 / 128, Bn / 128), 256, 0, stream>>>(
      U, W1, 2048, S, A, U2, Zp, XH, nullptr);

  // GEMM2: H2 = U2(16384x1024) @ W2^T(512x1024), fused final epilogue -> d_out
  gemm_bt<2><<<dim3(512 / 128, Bn / 128), 256, 0, stream>>>(
      U2, W2, 1024, S, A, U2, Zp, XH, (float*)d_out);
}